// Round 2
// baseline (5711.684 us; speedup 1.0000x reference)
//
#include <hip/hip_runtime.h>
#include <hip/hip_bf16.h>
#include <math.h>

#define BATCH 8
#define SEQ   1024
#define DMODEL 768
#define DEPTH 12
#define NHEAD 12
#define DHEAD 64
#define DFF   3072
#define MROWS (BATCH*SEQ)        // 8192
#define QKVN  (3*DMODEL)         // 2304

typedef __attribute__((ext_vector_type(8))) short bf16x8;
typedef __attribute__((ext_vector_type(4))) float f32x4;

__device__ __forceinline__ void gld16(const void* g, void* l) {
    __builtin_amdgcn_global_load_lds(
        (const __attribute__((address_space(1))) void*)g,
        (__attribute__((address_space(3))) void*)l, 16, 0, 0);
}
__device__ __forceinline__ unsigned short bf16b(float f) {
    __hip_bfloat16 hb = __float2bfloat16(f);
    return *(unsigned short*)&hb;
}

// ---------------- LayerNorm: fp32 in, bf16 or fp32 out ----------------
template<int BF16OUT>
__global__ __launch_bounds__(256) void ln_kernel(
    const float* __restrict__ in, void* __restrict__ outp,
    const float* __restrict__ w, const float* __restrict__ b)
{
    int row = blockIdx.x;
    const float* x = in + (size_t)row * DMODEL;
    int tid = threadIdx.x;

    float v[3];
    float lsum = 0.f, lsq = 0.f;
#pragma unroll
    for (int i = 0; i < 3; ++i) {
        v[i] = x[tid + i * 256];
        lsum += v[i];
        lsq  += v[i] * v[i];
    }
#pragma unroll
    for (int off = 32; off > 0; off >>= 1) {
        lsum += __shfl_down(lsum, off);
        lsq  += __shfl_down(lsq,  off);
    }
    __shared__ float red[10];
    int wave = tid >> 6, lane = tid & 63;
    if (lane == 0) { red[wave] = lsum; red[wave + 4] = lsq; }
    __syncthreads();
    if (tid == 0) {
        float s = red[0] + red[1] + red[2] + red[3];
        float q = red[4] + red[5] + red[6] + red[7];
        float mu = s * (1.0f / DMODEL);
        float var = q * (1.0f / DMODEL) - mu * mu;
        red[8] = mu;
        red[9] = rsqrtf(var + 1e-5f);
    }
    __syncthreads();
    float mu = red[8], rs = red[9];
#pragma unroll
    for (int i = 0; i < 3; ++i) {
        int c = tid + i * 256;
        float o = (v[i] - mu) * rs * w[c] + b[c];
        if (BF16OUT) ((__hip_bfloat16*)outp)[(size_t)row * DMODEL + c] = __float2bfloat16(o);
        else         ((float*)outp)[(size_t)row * DMODEL + c] = o;
    }
}

// ---------------- Weight transpose+convert: W[K,N] fp32 -> Wt[N,K] bf16 ----------------
__global__ __launch_bounds__(256) void transpose_w(
    const float* __restrict__ W, __hip_bfloat16* __restrict__ Wt, int K, int N)
{
    __shared__ float T[64][65];
    int tid = threadIdx.x;
    int tx = tid & 63, ty = tid >> 6;
    int n0 = blockIdx.x * 64, k0 = blockIdx.y * 64;
#pragma unroll
    for (int i = 0; i < 16; ++i)
        T[ty + 4 * i][tx] = W[(size_t)(k0 + ty + 4 * i) * N + n0 + tx];
    __syncthreads();
#pragma unroll
    for (int i = 0; i < 16; ++i)
        Wt[(size_t)(n0 + ty + 4 * i) * K + k0 + tx] = __float2bfloat16(T[tx][ty + 4 * i]);
}

// ---------------- V transpose: qkv V-part [seq][h*64+d] -> vt [b][h][d][seq] ----------------
__global__ __launch_bounds__(256) void transpose_v(
    const __hip_bfloat16* __restrict__ qkv, __hip_bfloat16* __restrict__ vt)
{
    __shared__ unsigned int T[64 * 33];   // row stride 33 dwords = 66 bf16
    int tid = threadIdx.x;
    int s0 = blockIdx.x * 64, h = blockIdx.y, b = blockIdx.z;
    const __hip_bfloat16* src = qkv + ((size_t)(b * SEQ + s0)) * QKVN + 2 * DMODEL + h * DHEAD;
#pragma unroll
    for (int p = 0; p < 2; ++p) {
        int row = (tid >> 3) + 32 * p;
        int c8 = tid & 7;
        uint4 v = *(const uint4*)(src + (size_t)row * QKVN + c8 * 8);
        unsigned int* dst = &T[row * 33 + c8 * 4];
        dst[0] = v.x; dst[1] = v.y; dst[2] = v.z; dst[3] = v.w;
    }
    __syncthreads();
    __hip_bfloat16* ob = vt + ((size_t)(b * NHEAD + h)) * DHEAD * SEQ;
    const unsigned short* Ts = (const unsigned short*)T;
#pragma unroll
    for (int p = 0; p < 2; ++p) {
        int d = (tid >> 3) + 32 * p;
        int sb = (tid & 7) * 8;
        unsigned int wds[4];
#pragma unroll
        for (int j = 0; j < 4; ++j) {
            unsigned int lo = Ts[(size_t)(sb + 2 * j) * 66 + d];
            unsigned int hi = Ts[(size_t)(sb + 2 * j + 1) * 66 + d];
            wds[j] = lo | (hi << 16);
        }
        *(uint4*)(ob + (size_t)d * SEQ + s0 + sb) = *(const uint4*)wds;
    }
}

// ---------------- bf16 MFMA GEMM: double-buffered LDS, pipelined (T3 min 2-phase) ----------------
// Per k-step: issue next tile's global_load_lds BEFORE computing current tile;
// single __syncthreads() per step (vmcnt(0) drain lands AFTER the MFMAs, so
// load latency hides under compute instead of serializing against it).
template<int HAS_BIAS, int ACT_GELU, int HAS_RES, int OUT_BF16>
__global__ __launch_bounds__(256) void gemm_bf16(
    const __hip_bfloat16* __restrict__ A, const __hip_bfloat16* __restrict__ Bt,
    const float* __restrict__ bias, const float* __restrict__ resid,
    void* __restrict__ Cout, int M, int N, int K)
{
    __shared__ __hip_bfloat16 Afr[2][16 * 512];   // 2 x 16 KB
    __shared__ __hip_bfloat16 Bfr[2][16 * 512];   // 2 x 16 KB  (total 64 KB -> 2 blocks/CU)

    int tid = threadIdx.x;
    int lane = tid & 63;
    int w = tid >> 6;
    int wm = w >> 1, wn = w & 1;
    int m0 = blockIdx.y * 128;
    int n0 = blockIdx.x * 128;
    int l15 = lane & 15;
    int quad = lane >> 4;

    // precompute per-thread global offsets for the 4 staged chunks (k0 added later)
    int c0 = w * 4;
    size_t aoff[4], boff[4];
#pragma unroll
    for (int i = 0; i < 4; ++i) {
        int c = c0 + i;
        int row = ((c >> 3) << 6) + ((c & 3) << 4) + l15;
        int kc  = (((c >> 2) & 1) << 5) + (quad << 3);
        aoff[i] = (size_t)(m0 + row) * K + kc;
        boff[i] = (size_t)(n0 + row) * K + kc;
    }

    auto stage = [&](int buf, int k0) {
#pragma unroll
        for (int i = 0; i < 4; ++i) {
            gld16(A  + aoff[i] + k0, &Afr[buf][(c0 + i) * 512]);
            gld16(Bt + boff[i] + k0, &Bfr[buf][(c0 + i) * 512]);
        }
    };

    f32x4 acc[4][4];
#pragma unroll
    for (int i = 0; i < 4; ++i)
#pragma unroll
        for (int j = 0; j < 4; ++j) {
            f32x4 z = {0.f, 0.f, 0.f, 0.f};
            acc[i][j] = z;
        }

    auto kstep = [&](int buf) {
#pragma unroll
        for (int t = 0; t < 2; ++t) {
            bf16x8 a[4], b[4];
#pragma unroll
            for (int f = 0; f < 4; ++f) {
                a[f] = *(const bf16x8*)&Afr[buf][(wm * 8 + t * 4 + f) * 512 + lane * 8];
                b[f] = *(const bf16x8*)&Bfr[buf][(wn * 8 + t * 4 + f) * 512 + lane * 8];
            }
#pragma unroll
            for (int i = 0; i < 4; ++i)
#pragma unroll
                for (int j = 0; j < 4; ++j)
                    acc[i][j] = __builtin_amdgcn_mfma_f32_16x16x32_bf16(
                        a[i], b[j], acc[i][j], 0, 0, 0);
        }
    };

    int nsteps = K >> 6;
    stage(0, 0);
    __syncthreads();                 // buf0 resident
    int cur = 0;
    for (int ks = 1; ks < nsteps; ++ks) {
        stage(cur ^ 1, ks << 6);     // issue next tile (waited only at the barrier below)
        kstep(cur);                  // compute current tile
        __syncthreads();             // drains vmcnt (next tile ready) + lgkm (cur reads done)
        cur ^= 1;
    }
    kstep(cur);                      // last tile

#pragma unroll
    for (int i = 0; i < 4; ++i) {
#pragma unroll
        for (int j = 0; j < 4; ++j) {
            int col = n0 + wn * 64 + j * 16 + l15;
            float bv = HAS_BIAS ? bias[col] : 0.f;
#pragma unroll
            for (int r = 0; r < 4; ++r) {
                int row = m0 + wm * 64 + i * 16 + quad * 4 + r;
                float val = acc[i][j][r] + bv;
                if (ACT_GELU) val = 0.5f * val * (1.0f + erff(val * 0.70710678118f));
                if (HAS_RES)  val += resid[(size_t)row * N + col];
                if (OUT_BF16) ((__hip_bfloat16*)Cout)[(size_t)row * N + col] = __float2bfloat16(val);
                else          ((float*)Cout)[(size_t)row * N + col] = val;
            }
        }
    }
}

// ---------------- MFMA flash attention (K/V staging double-buffered + pipelined) ----------------
// Block: 256 thr / 4 waves; 128 q-rows per block (32 per wave); ktile = 64 kpos.
// S^T = K.Q^T (C-layout: col=q=l15 -> softmax state lane-indexed, quad-uniform).
// P C-rows are kpos-contiguous -> b64 LDS writes; PV: O^T = Vt.P (A=Vt frag, B=P frag).
__global__ __launch_bounds__(256) void fattn_mfma(
    const __hip_bfloat16* __restrict__ qkv,
    const __hip_bfloat16* __restrict__ vt,
    __hip_bfloat16* __restrict__ out)
{
    // layout: K[0],K[1] | V[0],V[1] | P/Qstage
    __shared__ __align__(16) char lds[2 * 8192 + 2 * 8192 + 4 * 4608];

    int tid = threadIdx.x;
    int lane = tid & 63;
    int w = tid >> 6;
    int l15 = lane & 15, quad = lane >> 4;
    int qt = blockIdx.x, h = blockIdx.y, b = blockIdx.z;

    char* Pbase = lds + 32768;
    unsigned short* Pw = (unsigned short*)(Pbase + w * 4608);   // [32 q][72] bf16

    const int q0 = qt * 128 + w * 32;   // seq offset of this wave's 32 q-rows
    const __hip_bfloat16* Qp = qkv + ((size_t)(b * SEQ + q0)) * QKVN + h * DHEAD;
    const __hip_bfloat16* Kp = qkv + ((size_t)(b * SEQ)) * QKVN + DMODEL + h * DHEAD;
    const __hip_bfloat16* Vp = vt + ((size_t)(b * NHEAD + h)) * DHEAD * SEQ;

    auto fstage = [&](int buf, int kt) {
#pragma unroll
        for (int i = 0; i < 4; ++i) {
            int c = w * 4 + i;
            if (c < 8) {   // K chunk: ks = c>>1, kh = c&1
                gld16(Kp + (size_t)(kt * 64 + ((c >> 1) << 4) + l15) * QKVN
                         + ((c & 1) << 5) + quad * 8,
                      lds + buf * 8192 + c * 1024);
            } else {       // Vt chunk: ds = (c-8)>>1, kh = (c-8)&1
                int c2 = c - 8;
                gld16(Vp + (size_t)(((c2 >> 1) << 4) + l15) * SEQ
                         + kt * 64 + ((c2 & 1) << 5) + quad * 8,
                      lds + 16384 + buf * 8192 + c2 * 1024);
            }
        }
    };

    // stage Q frags through P region (chunk c = w*4 + qs*2 + kh), plus first K/V tile
#pragma unroll
    for (int i = 0; i < 4; ++i) {
        int qs = i >> 1, kh = i & 1;
        gld16(Qp + (size_t)(qs * 16 + l15) * QKVN + kh * 32 + quad * 8,
              Pbase + (w * 4 + i) * 1024);
    }
    fstage(0, 0);
    __syncthreads();                 // Q + first K/V tile resident
    bf16x8 qf[2][2];
#pragma unroll
    for (int i = 0; i < 4; ++i)
        qf[i >> 1][i & 1] = *(const bf16x8*)(Pbase + (w * 4 + i) * 1024 + lane * 16);
    __syncthreads();                 // all waves' Q reads done before any P write

    float m_st[2] = {-1e30f, -1e30f};
    float l_st[2] = {0.f, 0.f};
    f32x4 accO[2][4];
#pragma unroll
    for (int qs = 0; qs < 2; ++qs)
#pragma unroll
        for (int ds = 0; ds < 4; ++ds) {
            f32x4 z = {0.f, 0.f, 0.f, 0.f};
            accO[qs][ds] = z;
        }

    int fb = 0;
    for (int kt = 0; kt < 16; ++kt) {
        if (kt < 15) fstage(fb ^ 1, kt + 1);   // prefetch next tile under compute

        char* Kfb = lds + fb * 8192;
        char* Vfb = lds + 16384 + fb * 8192;

        // S^T: sA[qs][ks], D row = kpos = ks*16+quad*4+r, col = q = l15
        f32x4 sA[2][4];
#pragma unroll
        for (int qs = 0; qs < 2; ++qs)
#pragma unroll
            for (int ks = 0; ks < 4; ++ks) {
                f32x4 z = {0.f, 0.f, 0.f, 0.f};
                sA[qs][ks] = z;
            }
#pragma unroll
        for (int ks = 0; ks < 4; ++ks)
#pragma unroll
            for (int kh = 0; kh < 2; ++kh) {
                bf16x8 kf = *(const bf16x8*)(Kfb + (ks * 2 + kh) * 1024 + lane * 16);
                sA[0][ks] = __builtin_amdgcn_mfma_f32_16x16x32_bf16(kf, qf[0][kh], sA[0][ks], 0, 0, 0);
                sA[1][ks] = __builtin_amdgcn_mfma_f32_16x16x32_bf16(kf, qf[1][kh], sA[1][ks], 0, 0, 0);
            }

        // online softmax per qs (state indexed by q = l15, uniform across quads)
#pragma unroll
        for (int qs = 0; qs < 2; ++qs) {
            float rm = sA[qs][0][0];
#pragma unroll
            for (int ks = 0; ks < 4; ++ks)
#pragma unroll
                for (int r = 0; r < 4; ++r) rm = fmaxf(rm, sA[qs][ks][r]);
            rm = fmaxf(rm, __shfl_xor(rm, 16));
            rm = fmaxf(rm, __shfl_xor(rm, 32));
            float mnew = fmaxf(m_st[qs], rm * 0.125f);
            float alpha = __expf(m_st[qs] - mnew);
            m_st[qs] = mnew;
            float sum = 0.f;
            unsigned short pb[4][4];
#pragma unroll
            for (int ks = 0; ks < 4; ++ks)
#pragma unroll
                for (int r = 0; r < 4; ++r) {
                    float p = __expf(sA[qs][ks][r] * 0.125f - mnew);
                    sum += p;
                    pb[ks][r] = bf16b(p);
                }
            sum += __shfl_xor(sum, 16);
            sum += __shfl_xor(sum, 32);
            l_st[qs] = l_st[qs] * alpha + sum;
#pragma unroll
            for (int ds = 0; ds < 4; ++ds) accO[qs][ds] *= alpha;
            // P write: rows kpos contiguous -> b64 per ks
#pragma unroll
            for (int ks = 0; ks < 4; ++ks) {
                unsigned int lo = pb[ks][0] | ((unsigned int)pb[ks][1] << 16);
                unsigned int hi = pb[ks][2] | ((unsigned int)pb[ks][3] << 16);
                unsigned int* dst = (unsigned int*)(Pw + (qs * 16 + l15) * 72 + ks * 16 + quad * 4);
                dst[0] = lo; dst[1] = hi;
            }
        }

        // PV: O^T[d][q] += Vt . P   (same-wave P, no barrier)
#pragma unroll
        for (int kh = 0; kh < 2; ++kh) {
            bf16x8 vf[4];
#pragma unroll
            for (int ds = 0; ds < 4; ++ds)
                vf[ds] = *(const bf16x8*)(Vfb + (ds * 2 + kh) * 1024 + lane * 16);
#pragma unroll
            for (int qs = 0; qs < 2; ++qs) {
                bf16x8 pf = *(const bf16x8*)(Pw + (qs * 16 + l15) * 72 + kh * 32 + quad * 8);
#pragma unroll
                for (int ds = 0; ds < 4; ++ds)
                    accO[qs][ds] = __builtin_amdgcn_mfma_f32_16x16x32_bf16(
                        vf[ds], pf, accO[qs][ds], 0, 0, 0);
            }
        }

        __syncthreads();   // drains vmcnt (next tile staged) + all reads of tile fb done
        fb ^= 1;
    }

    // epilogue: normalize, transpose O^T -> natural through Pw, coalesced store
#pragma unroll
    for (int qs = 0; qs < 2; ++qs) {
        float inv = 1.0f / l_st[qs];
#pragma unroll
        for (int ds = 0; ds < 4; ++ds) {
            unsigned short u[4];
#pragma unroll
            for (int r = 0; r < 4; ++r) u[r] = bf16b(accO[qs][ds][r] * inv);
            unsigned int lo = u[0] | ((unsigned int)u[1] << 16);
            unsigned int hi = u[2] | ((unsigned int)u[3] << 16);
            unsigned int* dst = (unsigned int*)(Pw + (qs * 16 + l15) * 72 + ds * 16 + quad * 4);
            dst[0] = lo; dst[1] = hi;
        }
    }
    __hip_bfloat16* ob = out + ((size_t)(b * SEQ + q0)) * DMODEL + h * DHEAD;
#pragma unroll
    for (int i = 0; i < 4; ++i) {
        int row = i * 8 + (lane >> 3);
        uint4 v = *(const uint4*)(Pw + row * 72 + (lane & 7) * 8);
        *(uint4*)(ob + (size_t)row * DMODEL + (lane & 7) * 8) = v;
    }
}

// ---------------- Launcher ----------------
extern "C" void kernel_launch(void* const* d_in, const int* in_sizes, int n_in,
                              void* d_out, int out_size, void* d_ws, size_t ws_size,
                              hipStream_t stream)
{
    const float* x      = (const float*)d_in[0];
    const float* ln1_w  = (const float*)d_in[1];
    const float* ln1_b  = (const float*)d_in[2];
    const float* w_qkv  = (const float*)d_in[3];
    const float* w_o    = (const float*)d_in[4];
    const float* b_o    = (const float*)d_in[5];
    const float* ln2_w  = (const float*)d_in[6];
    const float* ln2_b  = (const float*)d_in[7];
    const float* w1     = (const float*)d_in[8];
    const float* b1     = (const float*)d_in[9];
    const float* w2     = (const float*)d_in[10];
    const float* b2     = (const float*)d_in[11];
    const float* lnf_w  = (const float*)d_in[12];
    const float* lnf_b  = (const float*)d_in[13];

    char* p = (char*)d_ws;
    float* xbuf = (float*)p;                   p += (size_t)MROWS * DMODEL * 4;
    __hip_bfloat16* qkv  = (__hip_bfloat16*)p; p += (size_t)MROWS * QKVN * 2;
    __hip_bfloat16* hbuf = (__hip_bfloat16*)p; p += (size_t)MROWS * DMODEL * 2;
    __hip_bfloat16* ffn1 = (__hip_bfloat16*)p; p += (size_t)MROWS * DFF * 2;
    __hip_bfloat16* wq_t = (__hip_bfloat16*)p; p += (size_t)QKVN * DMODEL * 2;
    __hip_bfloat16* wo_t = (__hip_bfloat16*)p; p += (size_t)DMODEL * DMODEL * 2;
    __hip_bfloat16* w1_t = (__hip_bfloat16*)p; p += (size_t)DFF * DMODEL * 2;
    __hip_bfloat16* w2_t = (__hip_bfloat16*)p; p += (size_t)DMODEL * DFF * 2;
    __hip_bfloat16* vtb  = (__hip_bfloat16*)p; p += (size_t)MROWS * DMODEL * 2;

    hipError_t e = hipMemcpyAsync(xbuf, x, (size_t)MROWS * DMODEL * sizeof(float),
                                  hipMemcpyDeviceToDevice, stream);
    (void)e;

    for (int l = 0; l < DEPTH; ++l) {
        const float* l1w = ln1_w + (size_t)l * DMODEL;
        const float* l1b = ln1_b + (size_t)l * DMODEL;
        const float* wq  = w_qkv + (size_t)l * DMODEL * QKVN;
        const float* wo  = w_o   + (size_t)l * DMODEL * DMODEL;
        const float* bo  = b_o   + (size_t)l * DMODEL;
        const float* l2w = ln2_w + (size_t)l * DMODEL;
        const float* l2b = ln2_b + (size_t)l * DMODEL;
        const float* W1  = w1    + (size_t)l * DMODEL * DFF;
        const float* B1  = b1    + (size_t)l * DFF;
        const float* W2  = w2    + (size_t)l * DFF * DMODEL;
        const float* B2  = b2    + (size_t)l * DMODEL;

        transpose_w<<<dim3(QKVN / 64, DMODEL / 64), 256, 0, stream>>>(wq, wq_t, DMODEL, QKVN);
        transpose_w<<<dim3(DMODEL / 64, DMODEL / 64), 256, 0, stream>>>(wo, wo_t, DMODEL, DMODEL);
        transpose_w<<<dim3(DFF / 64, DMODEL / 64), 256, 0, stream>>>(W1, w1_t, DMODEL, DFF);
        transpose_w<<<dim3(DMODEL / 64, DFF / 64), 256, 0, stream>>>(W2, w2_t, DFF, DMODEL);

        ln_kernel<1><<<MROWS, 256, 0, stream>>>(xbuf, hbuf, l1w, l1b);
        gemm_bf16<0,0,0,1><<<dim3(QKVN / 128, MROWS / 128), 256, 0, stream>>>(
            hbuf, wq_t, nullptr, nullptr, qkv, MROWS, QKVN, DMODEL);
        transpose_v<<<dim3(SEQ / 64, NHEAD, BATCH), 256, 0, stream>>>(qkv, vtb);
        fattn_mfma<<<dim3(SEQ / 128, NHEAD, BATCH), 256, 0, stream>>>(qkv, vtb, hbuf);
        gemm_bf16<1,0,1,0><<<dim3(DMODEL / 128, MROWS / 128), 256, 0, stream>>>(
            hbuf, wo_t, bo, xbuf, xbuf, MROWS, DMODEL, DMODEL);
        ln_kernel<1><<<MROWS, 256, 0, stream>>>(xbuf, hbuf, l2w, l2b);
        gemm_bf16<1,1,0,1><<<dim3(DFF / 128, MROWS / 128), 256, 0, stream>>>(
            hbuf, w1_t, B1, nullptr, ffn1, MROWS, DFF, DMODEL);
        gemm_bf16<1,0,1,0><<<dim3(DMODEL / 128, MROWS / 128), 256, 0, stream>>>(
            ffn1, w2_t, B2, xbuf, xbuf, MROWS, DMODEL, DFF);
    }

    ln_kernel<0><<<MROWS, 256, 0, stream>>>(xbuf, (float*)d_out, lnf_w, lnf_b);
}

// Round 3
// 4743.649 us; speedup vs baseline: 1.2041x; 1.2041x over previous
//
#include <hip/hip_runtime.h>
#include <hip/hip_bf16.h>
#include <math.h>

#define BATCH 8
#define SEQ   1024
#define DMODEL 768
#define DEPTH 12
#define NHEAD 12
#define DHEAD 64
#define DFF   3072
#define MROWS (BATCH*SEQ)        // 8192
#define QKVN  (3*DMODEL)         // 2304

typedef __attribute__((ext_vector_type(8))) short bf16x8;
typedef __attribute__((ext_vector_type(4))) float f32x4;

__device__ __forceinline__ void gld16(const void* g, void* l) {
    __builtin_amdgcn_global_load_lds(
        (const __attribute__((address_space(1))) void*)g,
        (__attribute__((address_space(3))) void*)l, 16, 0, 0);
}
__device__ __forceinline__ unsigned short bf16b(float f) {
    __hip_bfloat16 hb = __float2bfloat16(f);
    return *(unsigned short*)&hb;
}

// ---------------- LayerNorm: fp32 in, bf16 or fp32 out ----------------
template<int BF16OUT>
__global__ __launch_bounds__(256) void ln_kernel(
    const float* __restrict__ in, void* __restrict__ outp,
    const float* __restrict__ w, const float* __restrict__ b)
{
    int row = blockIdx.x;
    const float* x = in + (size_t)row * DMODEL;
    int tid = threadIdx.x;

    float v[3];
    float lsum = 0.f, lsq = 0.f;
#pragma unroll
    for (int i = 0; i < 3; ++i) {
        v[i] = x[tid + i * 256];
        lsum += v[i];
        lsq  += v[i] * v[i];
    }
#pragma unroll
    for (int off = 32; off > 0; off >>= 1) {
        lsum += __shfl_down(lsum, off);
        lsq  += __shfl_down(lsq,  off);
    }
    __shared__ float red[10];
    int wave = tid >> 6, lane = tid & 63;
    if (lane == 0) { red[wave] = lsum; red[wave + 4] = lsq; }
    __syncthreads();
    if (tid == 0) {
        float s = red[0] + red[1] + red[2] + red[3];
        float q = red[4] + red[5] + red[6] + red[7];
        float mu = s * (1.0f / DMODEL);
        float var = q * (1.0f / DMODEL) - mu * mu;
        red[8] = mu;
        red[9] = rsqrtf(var + 1e-5f);
    }
    __syncthreads();
    float mu = red[8], rs = red[9];
#pragma unroll
    for (int i = 0; i < 3; ++i) {
        int c = tid + i * 256;
        float o = (v[i] - mu) * rs * w[c] + b[c];
        if (BF16OUT) ((__hip_bfloat16*)outp)[(size_t)row * DMODEL + c] = __float2bfloat16(o);
        else         ((float*)outp)[(size_t)row * DMODEL + c] = o;
    }
}

// ---------------- Weight transpose+convert: W[K,N] fp32 -> Wt[N,K] bf16 ----------------
__global__ __launch_bounds__(256) void transpose_w(
    const float* __restrict__ W, __hip_bfloat16* __restrict__ Wt, int K, int N)
{
    __shared__ float T[64][65];
    int tid = threadIdx.x;
    int tx = tid & 63, ty = tid >> 6;
    int n0 = blockIdx.x * 64, k0 = blockIdx.y * 64;
#pragma unroll
    for (int i = 0; i < 16; ++i)
        T[ty + 4 * i][tx] = W[(size_t)(k0 + ty + 4 * i) * N + n0 + tx];
    __syncthreads();
#pragma unroll
    for (int i = 0; i < 16; ++i)
        Wt[(size_t)(n0 + ty + 4 * i) * K + k0 + tx] = __float2bfloat16(T[tx][ty + 4 * i]);
}

// ---------------- V transpose: qkv V-part [seq][h*64+d] -> vt [b][h][d][seq] ----------------
__global__ __launch_bounds__(256) void transpose_v(
    const __hip_bfloat16* __restrict__ qkv, __hip_bfloat16* __restrict__ vt)
{
    __shared__ unsigned int T[64 * 33];   // row stride 33 dwords = 66 bf16
    int tid = threadIdx.x;
    int s0 = blockIdx.x * 64, h = blockIdx.y, b = blockIdx.z;
    const __hip_bfloat16* src = qkv + ((size_t)(b * SEQ + s0)) * QKVN + 2 * DMODEL + h * DHEAD;
#pragma unroll
    for (int p = 0; p < 2; ++p) {
        int row = (tid >> 3) + 32 * p;
        int c8 = tid & 7;
        uint4 v = *(const uint4*)(src + (size_t)row * QKVN + c8 * 8);
        unsigned int* dst = &T[row * 33 + c8 * 4];
        dst[0] = v.x; dst[1] = v.y; dst[2] = v.z; dst[3] = v.w;
    }
    __syncthreads();
    __hip_bfloat16* ob = vt + ((size_t)(b * NHEAD + h)) * DHEAD * SEQ;
    const unsigned short* Ts = (const unsigned short*)T;
#pragma unroll
    for (int p = 0; p < 2; ++p) {
        int d = (tid >> 3) + 32 * p;
        int sb = (tid & 7) * 8;
        unsigned int wds[4];
#pragma unroll
        for (int j = 0; j < 4; ++j) {
            unsigned int lo = Ts[(size_t)(sb + 2 * j) * 66 + d];
            unsigned int hi = Ts[(size_t)(sb + 2 * j + 1) * 66 + d];
            wds[j] = lo | (hi << 16);
        }
        *(uint4*)(ob + (size_t)d * SEQ + s0 + sb) = *(const uint4*)wds;
    }
}

// ---------------- bf16 MFMA GEMM: BK=32 double-buffer, counted vmcnt, raw barriers ----------------
// 32 KB LDS total (same as round-0 single-buffer) -> occupancy preserved.
// Per k-step: stage(next buf) [4 gld16/wave] -> s_waitcnt vmcnt(4) (prev stage
// arrived, NEW stage stays in flight across the barrier) -> s_barrier ->
// ds_read + 16 MFMA -> s_barrier.  No vmcnt(0) drain in the main loop.
template<int HAS_BIAS, int ACT_GELU, int HAS_RES, int OUT_BF16>
__global__ __launch_bounds__(256) void gemm_bf16(
    const __hip_bfloat16* __restrict__ A, const __hip_bfloat16* __restrict__ Bt,
    const float* __restrict__ bias, const float* __restrict__ resid,
    void* __restrict__ Cout, int M, int N, int K)
{
    __shared__ __hip_bfloat16 Afr[2][8 * 512];   // 2 x 8 KB
    __shared__ __hip_bfloat16 Bfr[2][8 * 512];   // 2 x 8 KB  (32 KB total)

    int tid = threadIdx.x;
    int lane = tid & 63;
    int w = tid >> 6;
    int wm = w >> 1, wn = w & 1;
    int m0 = blockIdx.y * 128;
    int n0 = blockIdx.x * 128;
    int l15 = lane & 15;
    int quad = lane >> 4;

    // chunk c in [0,8): rows ((c>>2)<<6)+((c&3)<<4)+l15, k = quad*8 (BK=32)
    // wave w stages A chunks {2w, 2w+1} and B chunks {2w, 2w+1}
    int ca = w * 2;
    size_t aoff[2], boff[2];
#pragma unroll
    for (int i = 0; i < 2; ++i) {
        int c = ca + i;
        int row = ((c >> 2) << 6) + ((c & 3) << 4) + l15;
        aoff[i] = (size_t)(m0 + row) * K + quad * 8;
        boff[i] = (size_t)(n0 + row) * K + quad * 8;
    }

    auto stage = [&](int buf, int k0) {
#pragma unroll
        for (int i = 0; i < 2; ++i) {
            gld16(A  + aoff[i] + k0, &Afr[buf][(ca + i) * 512]);
            gld16(Bt + boff[i] + k0, &Bfr[buf][(ca + i) * 512]);
        }
    };

    f32x4 acc[4][4];
#pragma unroll
    for (int i = 0; i < 4; ++i)
#pragma unroll
        for (int j = 0; j < 4; ++j) {
            f32x4 z = {0.f, 0.f, 0.f, 0.f};
            acc[i][j] = z;
        }

    auto kstep = [&](int buf) {
        bf16x8 a[4], b[4];
#pragma unroll
        for (int f = 0; f < 4; ++f) {
            a[f] = *(const bf16x8*)&Afr[buf][(wm * 4 + f) * 512 + lane * 8];
            b[f] = *(const bf16x8*)&Bfr[buf][(wn * 4 + f) * 512 + lane * 8];
        }
#pragma unroll
        for (int i = 0; i < 4; ++i)
#pragma unroll
            for (int j = 0; j < 4; ++j)
                acc[i][j] = __builtin_amdgcn_mfma_f32_16x16x32_bf16(
                    a[i], b[j], acc[i][j], 0, 0, 0);
    };

    int nsteps = K >> 5;             // BK = 32
    stage(0, 0);                     // 4 loads in flight
    int cur = 0;
    for (int ks = 0; ks < nsteps - 1; ++ks) {
        stage(cur ^ 1, (ks + 1) << 5);               // +4 loads (8 in flight)
        asm volatile("s_waitcnt vmcnt(4)" ::: "memory");  // prev stage arrived
        __builtin_amdgcn_s_barrier();                 // all waves: tile ready
        __builtin_amdgcn_sched_barrier(0);            // no ds_read hoisting
        kstep(cur);                                   // reads retire before MFMA issue
        __builtin_amdgcn_s_barrier();                 // all reads done before overwrite
        cur ^= 1;
    }
    asm volatile("s_waitcnt vmcnt(0)" ::: "memory");
    __builtin_amdgcn_s_barrier();
    __builtin_amdgcn_sched_barrier(0);
    kstep(cur);                      // last tile

#pragma unroll
    for (int i = 0; i < 4; ++i) {
#pragma unroll
        for (int j = 0; j < 4; ++j) {
            int col = n0 + wn * 64 + j * 16 + l15;
            float bv = HAS_BIAS ? bias[col] : 0.f;
#pragma unroll
            for (int r = 0; r < 4; ++r) {
                int row = m0 + wm * 64 + i * 16 + quad * 4 + r;
                float val = acc[i][j][r] + bv;
                if (ACT_GELU) val = 0.5f * val * (1.0f + erff(val * 0.70710678118f));
                if (HAS_RES)  val += resid[(size_t)row * N + col];
                if (OUT_BF16) ((__hip_bfloat16*)Cout)[(size_t)row * N + col] = __float2bfloat16(val);
                else          ((float*)Cout)[(size_t)row * N + col] = val;
            }
        }
    }
}

// ---------------- MFMA flash attention (round-0 version, single-buffered) ----------------
// Block: 256 thr / 4 waves; 128 q-rows per block (32 per wave); ktile = 64 kpos.
// S^T = K.Q^T (C-layout: col=q=l15 -> softmax state lane-indexed, quad-uniform).
// P C-rows are kpos-contiguous -> b64 LDS writes; PV: O^T = Vt.P (A=Vt frag, B=P frag).
__global__ __launch_bounds__(256) void fattn_mfma(
    const __hip_bfloat16* __restrict__ qkv,
    const __hip_bfloat16* __restrict__ vt,
    __hip_bfloat16* __restrict__ out)
{
    __shared__ __align__(16) char lds[8192 + 8192 + 4 * 4608];   // Kfr, Vfr, P/Qst
    char* Kfr = lds;
    char* Vfr = lds + 8192;
    char* Pbase = lds + 16384;

    int tid = threadIdx.x;
    int lane = tid & 63;
    int w = tid >> 6;
    int l15 = lane & 15, quad = lane >> 4;
    int qt = blockIdx.x, h = blockIdx.y, b = blockIdx.z;

    unsigned short* Pw = (unsigned short*)(Pbase + w * 4608);   // [32 q][72] bf16

    const int q0 = qt * 128 + w * 32;   // seq offset of this wave's 32 q-rows
    const __hip_bfloat16* Qp = qkv + ((size_t)(b * SEQ + q0)) * QKVN + h * DHEAD;
    const __hip_bfloat16* Kp = qkv + ((size_t)(b * SEQ)) * QKVN + DMODEL + h * DHEAD;
    const __hip_bfloat16* Vp = vt + ((size_t)(b * NHEAD + h)) * DHEAD * SEQ;

    // stage Q frags through P region (chunk c = w*4 + qs*2 + kh)
#pragma unroll
    for (int i = 0; i < 4; ++i) {
        int qs = i >> 1, kh = i & 1;
        gld16(Qp + (size_t)(qs * 16 + l15) * QKVN + kh * 32 + quad * 8,
              Pbase + (w * 4 + i) * 1024);
    }
    __syncthreads();
    bf16x8 qf[2][2];
#pragma unroll
    for (int i = 0; i < 4; ++i)
        qf[i >> 1][i & 1] = *(const bf16x8*)(Pbase + (w * 4 + i) * 1024 + lane * 16);
    // no barrier needed: first loop barrier orders Q reads before any P write

    float m_st[2] = {-1e30f, -1e30f};
    float l_st[2] = {0.f, 0.f};
    f32x4 accO[2][4];
#pragma unroll
    for (int qs = 0; qs < 2; ++qs)
#pragma unroll
        for (int ds = 0; ds < 4; ++ds) {
            f32x4 z = {0.f, 0.f, 0.f, 0.f};
            accO[qs][ds] = z;
        }

    for (int kt = 0; kt < 16; ++kt) {
        __syncthreads();   // prior iter's Kfr/Vfr reads complete
#pragma unroll
        for (int i = 0; i < 4; ++i) {
            int c = w * 4 + i;
            if (c < 8) {   // K chunk: ks = c>>1, kh = c&1
                gld16(Kp + (size_t)(kt * 64 + ((c >> 1) << 4) + l15) * QKVN
                         + ((c & 1) << 5) + quad * 8,
                      Kfr + c * 1024);
            } else {       // Vt chunk: ds = (c-8)>>1, kh = (c-8)&1
                int c2 = c - 8;
                gld16(Vp + (size_t)(((c2 >> 1) << 4) + l15) * SEQ
                         + kt * 64 + ((c2 & 1) << 5) + quad * 8,
                      Vfr + c2 * 1024);
            }
        }
        __syncthreads();   // vmcnt drained: tiles visible

        // S^T: sA[qs][ks], D row = kpos = ks*16+quad*4+r, col = q = l15
        f32x4 sA[2][4];
#pragma unroll
        for (int qs = 0; qs < 2; ++qs)
#pragma unroll
            for (int ks = 0; ks < 4; ++ks) {
                f32x4 z = {0.f, 0.f, 0.f, 0.f};
                sA[qs][ks] = z;
            }
#pragma unroll
        for (int ks = 0; ks < 4; ++ks)
#pragma unroll
            for (int kh = 0; kh < 2; ++kh) {
                bf16x8 kf = *(const bf16x8*)(Kfr + (ks * 2 + kh) * 1024 + lane * 16);
                sA[0][ks] = __builtin_amdgcn_mfma_f32_16x16x32_bf16(kf, qf[0][kh], sA[0][ks], 0, 0, 0);
                sA[1][ks] = __builtin_amdgcn_mfma_f32_16x16x32_bf16(kf, qf[1][kh], sA[1][ks], 0, 0, 0);
            }

        // online softmax per qs (state indexed by q = l15, uniform across quads)
#pragma unroll
        for (int qs = 0; qs < 2; ++qs) {
            float rm = sA[qs][0][0];
#pragma unroll
            for (int ks = 0; ks < 4; ++ks)
#pragma unroll
                for (int r = 0; r < 4; ++r) rm = fmaxf(rm, sA[qs][ks][r]);
            rm = fmaxf(rm, __shfl_xor(rm, 16));
            rm = fmaxf(rm, __shfl_xor(rm, 32));
            float mnew = fmaxf(m_st[qs], rm * 0.125f);
            float alpha = __expf(m_st[qs] - mnew);
            m_st[qs] = mnew;
            float sum = 0.f;
            unsigned short pb[4][4];
#pragma unroll
            for (int ks = 0; ks < 4; ++ks)
#pragma unroll
                for (int r = 0; r < 4; ++r) {
                    float p = __expf(sA[qs][ks][r] * 0.125f - mnew);
                    sum += p;
                    pb[ks][r] = bf16b(p);
                }
            sum += __shfl_xor(sum, 16);
            sum += __shfl_xor(sum, 32);
            l_st[qs] = l_st[qs] * alpha + sum;
#pragma unroll
            for (int ds = 0; ds < 4; ++ds) accO[qs][ds] *= alpha;
            // P write: rows kpos contiguous -> b64 per ks
#pragma unroll
            for (int ks = 0; ks < 4; ++ks) {
                unsigned int lo = pb[ks][0] | ((unsigned int)pb[ks][1] << 16);
                unsigned int hi = pb[ks][2] | ((unsigned int)pb[ks][3] << 16);
                unsigned int* dst = (unsigned int*)(Pw + (qs * 16 + l15) * 72 + ks * 16 + quad * 4);
                dst[0] = lo; dst[1] = hi;
            }
        }

        // PV: O^T[d][q] += Vt . P   (same-wave P, no barrier)
#pragma unroll
        for (int kh = 0; kh < 2; ++kh) {
            bf16x8 vf[4];
#pragma unroll
            for (int ds = 0; ds < 4; ++ds)
                vf[ds] = *(const bf16x8*)(Vfr + (ds * 2 + kh) * 1024 + lane * 16);
#pragma unroll
            for (int qs = 0; qs < 2; ++qs) {
                bf16x8 pf = *(const bf16x8*)(Pw + (qs * 16 + l15) * 72 + kh * 32 + quad * 8);
#pragma unroll
                for (int ds = 0; ds < 4; ++ds)
                    accO[qs][ds] = __builtin_amdgcn_mfma_f32_16x16x32_bf16(
                        vf[ds], pf, accO[qs][ds], 0, 0, 0);
            }
        }
    }

    // epilogue: normalize, transpose O^T -> natural through Pw, coalesced store
#pragma unroll
    for (int qs = 0; qs < 2; ++qs) {
        float inv = 1.0f / l_st[qs];
#pragma unroll
        for (int ds = 0; ds < 4; ++ds) {
            unsigned short u[4];
#pragma unroll
            for (int r = 0; r < 4; ++r) u[r] = bf16b(accO[qs][ds][r] * inv);
            unsigned int lo = u[0] | ((unsigned int)u[1] << 16);
            unsigned int hi = u[2] | ((unsigned int)u[3] << 16);
            unsigned int* dst = (unsigned int*)(Pw + (qs * 16 + l15) * 72 + ds * 16 + quad * 4);
            dst[0] = lo; dst[1] = hi;
        }
    }
    __hip_bfloat16* ob = out + ((size_t)(b * SEQ + q0)) * DMODEL + h * DHEAD;
#pragma unroll
    for (int i = 0; i < 4; ++i) {
        int row = i * 8 + (lane >> 3);
        uint4 v = *(const uint4*)(Pw + row * 72 + (lane & 7) * 8);
        *(uint4*)(ob + (size_t)row * DMODEL + (lane & 7) * 8) = v;
    }
}

// ---------------- Launcher ----------------
extern "C" void kernel_launch(void* const* d_in, const int* in_sizes, int n_in,
                              void* d_out, int out_size, void* d_ws, size_t ws_size,
                              hipStream_t stream)
{
    const float* x      = (const float*)d_in[0];
    const float* ln1_w  = (const float*)d_in[1];
    const float* ln1_b  = (const float*)d_in[2];
    const float* w_qkv  = (const float*)d_in[3];
    const float* w_o    = (const float*)d_in[4];
    const float* b_o    = (const float*)d_in[5];
    const float* ln2_w  = (const float*)d_in[6];
    const float* ln2_b  = (const float*)d_in[7];
    const float* w1     = (const float*)d_in[8];
    const float* b1     = (const float*)d_in[9];
    const float* w2     = (const float*)d_in[10];
    const float* b2     = (const float*)d_in[11];
    const float* lnf_w  = (const float*)d_in[12];
    const float* lnf_b  = (const float*)d_in[13];

    char* p = (char*)d_ws;
    float* xbuf = (float*)p;                   p += (size_t)MROWS * DMODEL * 4;
    __hip_bfloat16* qkv  = (__hip_bfloat16*)p; p += (size_t)MROWS * QKVN * 2;
    __hip_bfloat16* hbuf = (__hip_bfloat16*)p; p += (size_t)MROWS * DMODEL * 2;
    __hip_bfloat16* ffn1 = (__hip_bfloat16*)p; p += (size_t)MROWS * DFF * 2;
    __hip_bfloat16* wq_t = (__hip_bfloat16*)p; p += (size_t)QKVN * DMODEL * 2;
    __hip_bfloat16* wo_t = (__hip_bfloat16*)p; p += (size_t)DMODEL * DMODEL * 2;
    __hip_bfloat16* w1_t = (__hip_bfloat16*)p; p += (size_t)DFF * DMODEL * 2;
    __hip_bfloat16* w2_t = (__hip_bfloat16*)p; p += (size_t)DMODEL * DFF * 2;
    __hip_bfloat16* vtb  = (__hip_bfloat16*)p; p += (size_t)MROWS * DMODEL * 2;

    hipError_t e = hipMemcpyAsync(xbuf, x, (size_t)MROWS * DMODEL * sizeof(float),
                                  hipMemcpyDeviceToDevice, stream);
    (void)e;

    for (int l = 0; l < DEPTH; ++l) {
        const float* l1w = ln1_w + (size_t)l * DMODEL;
        const float* l1b = ln1_b + (size_t)l * DMODEL;
        const float* wq  = w_qkv + (size_t)l * DMODEL * QKVN;
        const float* wo  = w_o   + (size_t)l * DMODEL * DMODEL;
        const float* bo  = b_o   + (size_t)l * DMODEL;
        const float* l2w = ln2_w + (size_t)l * DMODEL;
        const float* l2b = ln2_b + (size_t)l * DMODEL;
        const float* W1  = w1    + (size_t)l * DMODEL * DFF;
        const float* B1  = b1    + (size_t)l * DFF;
        const float* W2  = w2    + (size_t)l * DFF * DMODEL;
        const float* B2  = b2    + (size_t)l * DMODEL;

        transpose_w<<<dim3(QKVN / 64, DMODEL / 64), 256, 0, stream>>>(wq, wq_t, DMODEL, QKVN);
        transpose_w<<<dim3(DMODEL / 64, DMODEL / 64), 256, 0, stream>>>(wo, wo_t, DMODEL, DMODEL);
        transpose_w<<<dim3(DFF / 64, DMODEL / 64), 256, 0, stream>>>(W1, w1_t, DMODEL, DFF);
        transpose_w<<<dim3(DMODEL / 64, DFF / 64), 256, 0, stream>>>(W2, w2_t, DFF, DMODEL);

        ln_kernel<1><<<MROWS, 256, 0, stream>>>(xbuf, hbuf, l1w, l1b);
        gemm_bf16<0,0,0,1><<<dim3(QKVN / 128, MROWS / 128), 256, 0, stream>>>(
            hbuf, wq_t, nullptr, nullptr, qkv, MROWS, QKVN, DMODEL);
        transpose_v<<<dim3(SEQ / 64, NHEAD, BATCH), 256, 0, stream>>>(qkv, vtb);
        fattn_mfma<<<dim3(SEQ / 128, NHEAD, BATCH), 256, 0, stream>>>(qkv, vtb, hbuf);
        gemm_bf16<1,0,1,0><<<dim3(DMODEL / 128, MROWS / 128), 256, 0, stream>>>(
            hbuf, wo_t, bo, xbuf, xbuf, MROWS, DMODEL, DMODEL);
        ln_kernel<1><<<MROWS, 256, 0, stream>>>(xbuf, hbuf, l2w, l2b);
        gemm_bf16<1,1,0,1><<<dim3(DFF / 128, MROWS / 128), 256, 0, stream>>>(
            hbuf, w1_t, B1, nullptr, ffn1, MROWS, DFF, DMODEL);
        gemm_bf16<1,0,1,0><<<dim3(DMODEL / 128, MROWS / 128), 256, 0, stream>>>(
            ffn1, w2_t, B2, xbuf, xbuf, MROWS, DMODEL, DFF);
    }

    ln_kernel<0><<<MROWS, 256, 0, stream>>>(xbuf, (float*)d_out, lnf_w, lnf_b);
}